// Round 1
// baseline (1665.818 us; speedup 1.0000x reference)
//
#include <hip/hip_runtime.h>
#include <hip/hip_bf16.h>
#include <math.h>

// ---------------------------------------------------------------------------
// Problem constants (RelationAwareAttention): N=12224 rows, DIM=1024, H=16,
// D=64, B=64 images with contiguous ragged segments (lens sum = N).
// ---------------------------------------------------------------------------

#define DIMC 1024
#define NHEAD 16
#define HDIM 64

// ---------------- fp32 tiled GEMM with bias:  C = A[MxK] * W[KxN] + b -------
// BM=BN=64, BK=16, 256 threads, each thread 4x4 outputs.
constexpr int BM = 64, BN = 64, BK = 16;

__global__ __launch_bounds__(256) void gemm_bias_kernel(
    const float* __restrict__ A, const float* __restrict__ W,
    const float* __restrict__ bias, float* __restrict__ C,
    int M, int N, int K)
{
    __shared__ float As[BK][BM + 4];   // +4 pad keeps 16B alignment (272B rows)
    __shared__ float Bs[BK][BN + 4];

    const int t  = threadIdx.x;
    const int tx = t & 15;        // 0..15  -> output col group
    const int ty = t >> 4;        // 0..15  -> output row group
    const int row0 = blockIdx.x * BM;
    const int col0 = blockIdx.y * BN;

    float acc[4][4] = {};

    for (int k0 = 0; k0 < K; k0 += BK) {
        // --- load A tile (64 rows x 16 k), one float4 per thread ---
        {
            const int r  = t >> 2;            // 0..63
            const int kq = (t & 3) * 4;       // 0,4,8,12
            const float4 a4 = *(const float4*)(A + (size_t)(row0 + r) * K + k0 + kq);
            As[kq + 0][r] = a4.x;
            As[kq + 1][r] = a4.y;
            As[kq + 2][r] = a4.z;
            As[kq + 3][r] = a4.w;
        }
        // --- load B tile (16 k x 64 cols), one float4 per thread ---
        {
            const int kk = t >> 4;            // 0..15
            const int c4 = (t & 15) * 4;      // 0..60
            const float4 b4 = *(const float4*)(W + (size_t)(k0 + kk) * N + col0 + c4);
            *(float4*)&Bs[kk][c4] = b4;
        }
        __syncthreads();

        #pragma unroll
        for (int kk = 0; kk < BK; ++kk) {
            const float4 a4 = *(const float4*)&As[kk][ty * 4];
            const float4 b4 = *(const float4*)&Bs[kk][tx * 4];
            const float ar[4] = {a4.x, a4.y, a4.z, a4.w};
            const float br[4] = {b4.x, b4.y, b4.z, b4.w};
            #pragma unroll
            for (int i = 0; i < 4; ++i)
                #pragma unroll
                for (int j = 0; j < 4; ++j)
                    acc[i][j] += ar[i] * br[j];
        }
        __syncthreads();
    }

    #pragma unroll
    for (int i = 0; i < 4; ++i) {
        const int r = row0 + ty * 4 + i;
        #pragma unroll
        for (int j = 0; j < 4; ++j) {
            const int c = col0 + tx * 4 + j;
            C[(size_t)r * N + c] = acc[i][j] + bias[c];
        }
    }
}

// ---------------- flash attention over ragged contiguous segments ----------
// grid = B * NHEAD blocks; block handles (image b, head h).
// Each thread owns one query row (L <= 254 < 256).
// K/V staged in LDS in 64-key tiles; online softmax.
// Output written IN PLACE into v (this block owns rows [off,off+L) x cols
// [h*64,h*64+64) exclusively, and only reads that global slice during staging).
#define KT 64

__global__ __launch_bounds__(256) void attn_kernel(
    const float* __restrict__ q, const float* __restrict__ k,
    float* __restrict__ v,
    const int* __restrict__ lens, int B)
{
    __shared__ float ks[KT][HDIM];
    __shared__ float vs[KT][HDIM];

    const int b = blockIdx.x >> 4;      // / NHEAD
    const int h = blockIdx.x & 15;

    int off = 0;
    for (int i = 0; i < b; ++i) off += lens[i];
    const int L = lens[b];

    const int t = threadIdx.x;
    const bool active = (t < L);

    // load this thread's query row into registers
    float qreg[HDIM];
    {
        const float* qrow = q + (size_t)(off + (active ? t : 0)) * DIMC + h * HDIM;
        #pragma unroll
        for (int d = 0; d < HDIM; d += 4) {
            const float4 v4 = *(const float4*)(qrow + d);
            qreg[d] = v4.x; qreg[d+1] = v4.y; qreg[d+2] = v4.z; qreg[d+3] = v4.w;
        }
    }

    float m = -INFINITY, l = 0.f;
    float o[HDIM] = {};
    const float scale = 0.03125f;   // 1/sqrt(1024)

    for (int j0 = 0; j0 < L; j0 += KT) {
        const int tl = min(KT, L - j0);
        // stage K/V tile: tl rows x 64 cols (float4 per element-group)
        for (int idx = t; idx < tl * 16; idx += 256) {
            const int r  = idx >> 4;
            const int c4 = (idx & 15) * 4;
            const size_t g = (size_t)(off + j0 + r) * DIMC + h * HDIM + c4;
            *(float4*)&ks[r][c4] = *(const float4*)(k + g);
            *(float4*)&vs[r][c4] = *(const float4*)(v + g);
        }
        __syncthreads();

        if (active) {
            for (int j = 0; j < tl; ++j) {
                // dot(q, k_j) with 4 partial sums for ILP
                float s0 = 0.f, s1 = 0.f, s2 = 0.f, s3 = 0.f;
                #pragma unroll
                for (int d = 0; d < HDIM; d += 4) {
                    s0 += qreg[d+0] * ks[j][d+0];
                    s1 += qreg[d+1] * ks[j][d+1];
                    s2 += qreg[d+2] * ks[j][d+2];
                    s3 += qreg[d+3] * ks[j][d+3];
                }
                float s = ((s0 + s1) + (s2 + s3)) * scale;

                if (s > m) {
                    const float corr = __expf(m - s);   // exp(-inf)=0 on first key
                    l *= corr;
                    #pragma unroll
                    for (int d = 0; d < HDIM; ++d) o[d] *= corr;
                    m = s;
                }
                const float p = __expf(s - m);
                l += p;
                #pragma unroll
                for (int d = 0; d < HDIM; ++d) o[d] += p * vs[j][d];
            }
        }
        __syncthreads();
    }

    if (active) {
        const float inv = 1.f / l;
        float* orow = v + (size_t)(off + t) * DIMC + h * HDIM;
        #pragma unroll
        for (int d = 0; d < HDIM; d += 4) {
            float4 v4;
            v4.x = o[d]   * inv;
            v4.y = o[d+1] * inv;
            v4.z = o[d+2] * inv;
            v4.w = o[d+3] * inv;
            *(float4*)(orow + d) = v4;
        }
    }
}

// ---------------------------------------------------------------------------
extern "C" void kernel_launch(void* const* d_in, const int* in_sizes, int n_in,
                              void* d_out, int out_size, void* d_ws, size_t ws_size,
                              hipStream_t stream)
{
    const float* x   = (const float*)d_in[0];
    const float* Wq  = (const float*)d_in[1];
    const float* bq  = (const float*)d_in[2];
    const float* Wk  = (const float*)d_in[3];
    const float* bk  = (const float*)d_in[4];
    const float* Wv  = (const float*)d_in[5];
    const float* bv  = (const float*)d_in[6];
    const float* Wu  = (const float*)d_in[7];
    const float* bu  = (const float*)d_in[8];
    const int*  lens = (const int*)d_in[9];

    const int N = in_sizes[0] / DIMC;    // 12224
    const int B = in_sizes[9];           // 64

    float* out  = (float*)d_out;
    float* qbuf = (float*)d_out;                     // q scratch lives in d_out
    float* kbuf = (float*)d_ws;
    float* vbuf = kbuf + (size_t)N * DIMC;

    dim3 gblk(256);
    dim3 ggrid(N / BM, DIMC / BN);   // 191 x 16 (12224 = 191*64)

    // QKV projections
    gemm_bias_kernel<<<ggrid, gblk, 0, stream>>>(x, Wq, bq, qbuf, N, DIMC, DIMC);
    gemm_bias_kernel<<<ggrid, gblk, 0, stream>>>(x, Wk, bk, kbuf, N, DIMC, DIMC);
    gemm_bias_kernel<<<ggrid, gblk, 0, stream>>>(x, Wv, bv, vbuf, N, DIMC, DIMC);

    // attention (writes result in place into vbuf)
    attn_kernel<<<dim3(B * NHEAD), dim3(256), 0, stream>>>(qbuf, kbuf, vbuf, lens, B);

    // output projection (overwrites d_out; q no longer needed)
    gemm_bias_kernel<<<ggrid, gblk, 0, stream>>>(vbuf, Wu, bu, out, N, DIMC, DIMC);
}

// Round 2
// 477.058 us; speedup vs baseline: 3.4919x; 3.4919x over previous
//
#include <hip/hip_runtime.h>
#include <hip/hip_bf16.h>
#include <math.h>

#define DIMC 1024
#define NHEAD 16
#define HDIM 64
#define MPAD 12288   // 12224 padded up to multiple of 128

using bf16x8 = __attribute__((ext_vector_type(8))) short;
using f32x4  = __attribute__((ext_vector_type(4))) float;

__device__ inline ushort f2bf(float f) {          // round-to-nearest-even
    uint u = __float_as_uint(f);
    u += 0x7fffu + ((u >> 16) & 1u);
    return (ushort)(u >> 16);
}
__device__ inline float bf2f(ushort h) { return __uint_as_float(((uint)h) << 16); }

__device__ inline void gload_lds16(const ushort* g, ushort* l) {
    __builtin_amdgcn_global_load_lds(
        (const __attribute__((address_space(1))) uint*)g,
        (__attribute__((address_space(3))) uint*)l, 16, 0, 0);
}

// ---------------------------------------------------------------------------
// bf16 MFMA GEMM: C[M x 1024] = A[Mpad x 1024](bf16) * Bt[1024 x 1024]^T(bf16) + bias
// Bt is stored transposed: Bt[n][k] = B[k][n].  128x128 tile, BK=32, 4 waves.
// Stores guarded to gr < M.  Output fp32 or bf16.
// ---------------------------------------------------------------------------
template <bool BF16OUT>
__global__ __launch_bounds__(256) void gemm_mfma(
    const ushort* __restrict__ A, const ushort* __restrict__ Bt,
    const float* __restrict__ bias, void* __restrict__ Cout, int M)
{
    __shared__ ushort As[128 * 32];
    __shared__ ushort Bs[128 * 32];

    // XCD swizzle: 768 blocks, 768 % 8 == 0 -> each XCD walks one col-panel
    const int bid = blockIdx.x;
    const int cpx = gridDim.x >> 3;                 // 96
    const int swz = (bid & 7) * cpx + (bid >> 3);
    const int mt  = swz % 96;
    const int nt  = swz / 96;
    const int row0 = mt * 128, col0 = nt * 128;

    const int t    = threadIdx.x;
    const int w    = t >> 6;
    const int lane = t & 63;
    const int wr   = (w >> 1) * 64;                 // wave 2x2 -> 64x64 out each
    const int wc   = (w & 1) * 64;
    const int frow = lane & 15;
    const int fk   = (lane >> 4) * 8;

    const int arow = lane >> 2;                     // staging: row within 16-row chunk
    const int acol = (lane & 3) * 8;                // staging: k offset (8 bf16 = 16B)

    f32x4 acc[4][4] = {};

    for (int k0 = 0; k0 < DIMC; k0 += 32) {
        #pragma unroll
        for (int i = 0; i < 2; ++i) {
            const int rr = (i * 4 + w) * 16;        // 16-row chunk this wave stages
            gload_lds16(A  + (size_t)(row0 + rr + arow) * DIMC + k0 + acol, As + rr * 32);
            gload_lds16(Bt + (size_t)(col0 + rr + arow) * DIMC + k0 + acol, Bs + rr * 32);
        }
        __syncthreads();   // compiler emits vmcnt(0) drain before barrier

        bf16x8 af[4], bfr[4];
        #pragma unroll
        for (int m = 0; m < 4; ++m)
            af[m]  = *(const bf16x8*)&As[(wr + m * 16 + frow) * 32 + fk];
        #pragma unroll
        for (int n = 0; n < 4; ++n)
            bfr[n] = *(const bf16x8*)&Bs[(wc + n * 16 + frow) * 32 + fk];

        #pragma unroll
        for (int m = 0; m < 4; ++m)
            #pragma unroll
            for (int n = 0; n < 4; ++n)
                acc[m][n] = __builtin_amdgcn_mfma_f32_16x16x32_bf16(
                    af[m], bfr[n], acc[m][n], 0, 0, 0);
        __syncthreads();
    }

    // epilogue: C/D layout col = lane&15, row = (lane>>4)*4 + reg
    const int r4 = (lane >> 4) * 4;
    #pragma unroll
    for (int n = 0; n < 4; ++n) {
        const int c  = col0 + wc + n * 16 + (lane & 15);
        const float bb = bias[c];
        #pragma unroll
        for (int m = 0; m < 4; ++m) {
            #pragma unroll
            for (int r = 0; r < 4; ++r) {
                const int gr = row0 + wr + m * 16 + r4 + r;
                if (gr < M) {
                    const float val = acc[m][n][r] + bb;
                    if (BF16OUT) ((ushort*)Cout)[(size_t)gr * DIMC + c] = f2bf(val);
                    else         ((float*)Cout)[(size_t)gr * DIMC + c]  = val;
                }
            }
        }
    }
}

// ---------------------------------------------------------------------------
// x fp32 -> bf16, zero-pad rows [N, MPAD)
// ---------------------------------------------------------------------------
__global__ __launch_bounds__(256) void cvt_pad(
    const float* __restrict__ x, ushort* __restrict__ xb, int nvalid, int ntot)
{
    const int stride = gridDim.x * blockDim.x;
    for (int i = blockIdx.x * blockDim.x + threadIdx.x; i < ntot / 4; i += stride) {
        const int e = i * 4;
        ushort4 o;
        if (e < nvalid) {
            const float4 f = *(const float4*)(x + e);
            o.x = f2bf(f.x); o.y = f2bf(f.y); o.z = f2bf(f.z); o.w = f2bf(f.w);
        } else { o.x = o.y = o.z = o.w = 0; }
        *(ushort4*)(xb + e) = o;
    }
}

// ---------------------------------------------------------------------------
// W[k][n] fp32 -> Wt[n][k] bf16 (32x32 LDS tile transpose)
// ---------------------------------------------------------------------------
__global__ __launch_bounds__(256) void transpose_w_kernel(
    const float* __restrict__ W, ushort* __restrict__ Wt)
{
    __shared__ float tile[32][33];
    const int tx = threadIdx.x & 31;
    const int ty = threadIdx.x >> 5;
    const int n0 = blockIdx.x * 32;
    const int k0 = blockIdx.y * 32;
    #pragma unroll
    for (int i = 0; i < 32; i += 8)
        tile[ty + i][tx] = W[(size_t)(k0 + ty + i) * DIMC + n0 + tx];
    __syncthreads();
    #pragma unroll
    for (int i = 0; i < 32; i += 8)
        Wt[(size_t)(n0 + ty + i) * DIMC + k0 + tx] = f2bf(tile[tx][ty + i]);
}

// ---------------------------------------------------------------------------
// flash attention over ragged contiguous segments, bf16 in / bf16 out (in place
// into v).  One block per (image, head); thread = one query row (L <= 254).
// ---------------------------------------------------------------------------
__global__ __launch_bounds__(256) void attn_kernel(
    const ushort* __restrict__ q, const ushort* __restrict__ kk,
    ushort* __restrict__ vv, const int* __restrict__ lens)
{
    __shared__ float ks[64][64];
    __shared__ float vs[64][64];

    const int b = blockIdx.x >> 4;
    const int h = blockIdx.x & 15;
    int off = 0;
    for (int i = 0; i < b; ++i) off += lens[i];
    const int L = lens[b];

    const int t = threadIdx.x;
    const bool active = t < L;

    float qreg[64];
    {
        const uint4* qr = (const uint4*)(q + (size_t)(off + (active ? t : 0)) * DIMC + h * HDIM);
        #pragma unroll
        for (int c = 0; c < 8; ++c) {
            const uint4 u = qr[c];
            const uint uu[4] = {u.x, u.y, u.z, u.w};
            #pragma unroll
            for (int j = 0; j < 4; ++j) {
                qreg[c * 8 + j * 2]     = __uint_as_float(uu[j] << 16);
                qreg[c * 8 + j * 2 + 1] = __uint_as_float(uu[j] & 0xffff0000u);
            }
        }
    }

    float m = -INFINITY, l = 0.f;
    float o[64] = {};
    const float scale = 0.03125f;   // 1/sqrt(1024)

    for (int j0 = 0; j0 < L; j0 += 64) {
        const int tl = min(64, L - j0);
        for (int idx = t; idx < tl * 8; idx += 256) {
            const int r = idx >> 3;
            const int c = (idx & 7) * 8;
            const size_t g = (size_t)(off + j0 + r) * DIMC + h * HDIM + c;
            const uint4 uk = *(const uint4*)(kk + g);
            const uint4 uv = *(const uint4*)(vv + g);
            const uint ak[4] = {uk.x, uk.y, uk.z, uk.w};
            const uint av[4] = {uv.x, uv.y, uv.z, uv.w};
            #pragma unroll
            for (int j = 0; j < 4; ++j) {
                ks[r][c + j * 2]     = __uint_as_float(ak[j] << 16);
                ks[r][c + j * 2 + 1] = __uint_as_float(ak[j] & 0xffff0000u);
                vs[r][c + j * 2]     = __uint_as_float(av[j] << 16);
                vs[r][c + j * 2 + 1] = __uint_as_float(av[j] & 0xffff0000u);
            }
        }
        __syncthreads();

        if (active) {
            for (int j = 0; j < tl; ++j) {
                float s0 = 0.f, s1 = 0.f, s2 = 0.f, s3 = 0.f;
                #pragma unroll
                for (int d = 0; d < 64; d += 4) {
                    s0 += qreg[d + 0] * ks[j][d + 0];
                    s1 += qreg[d + 1] * ks[j][d + 1];
                    s2 += qreg[d + 2] * ks[j][d + 2];
                    s3 += qreg[d + 3] * ks[j][d + 3];
                }
                float s = ((s0 + s1) + (s2 + s3)) * scale;

                if (s > m) {
                    const float corr = __expf(m - s);   // exp(-inf)=0 first time
                    l *= corr;
                    #pragma unroll
                    for (int d = 0; d < 64; ++d) o[d] *= corr;
                    m = s;
                }
                const float p = __expf(s - m);
                l += p;
                #pragma unroll
                for (int d = 0; d < 64; ++d) o[d] += p * vs[j][d];
            }
        }
        __syncthreads();
    }

    if (active) {
        const float inv = 1.f / l;
        ushort* orow = vv + (size_t)(off + t) * DIMC + h * HDIM;
        #pragma unroll
        for (int d = 0; d < 64; d += 4) {
            ushort4 us;
            us.x = f2bf(o[d + 0] * inv);
            us.y = f2bf(o[d + 1] * inv);
            us.z = f2bf(o[d + 2] * inv);
            us.w = f2bf(o[d + 3] * inv);
            *(ushort4*)(orow + d) = us;
        }
    }
}

// ---------------------------------------------------------------------------
extern "C" void kernel_launch(void* const* d_in, const int* in_sizes, int n_in,
                              void* d_out, int out_size, void* d_ws, size_t ws_size,
                              hipStream_t stream)
{
    const float* x   = (const float*)d_in[0];
    const float* Wq  = (const float*)d_in[1];
    const float* bq  = (const float*)d_in[2];
    const float* Wk  = (const float*)d_in[3];
    const float* bk  = (const float*)d_in[4];
    const float* Wv  = (const float*)d_in[5];
    const float* bv  = (const float*)d_in[6];
    const float* Wu  = (const float*)d_in[7];
    const float* bu  = (const float*)d_in[8];
    const int*  lens = (const int*)d_in[9];

    const int N = in_sizes[0] / DIMC;    // 12224
    const int B = in_sizes[9];           // 64

    // ws layout (all bf16/ushort):
    ushort* xb  = (ushort*)d_ws;                         // MPAD*1024     (25.2 MB)
    ushort* wtq = xb  + (size_t)MPAD * DIMC;             // 1024*1024 x4  ( 8.4 MB)
    ushort* wtk = wtq + (size_t)DIMC * DIMC;
    ushort* wtv = wtk + (size_t)DIMC * DIMC;
    ushort* wtu = wtv + (size_t)DIMC * DIMC;
    ushort* kb  = wtu + (size_t)DIMC * DIMC;             // N*1024        (25.0 MB)
    ushort* vb  = kb  + (size_t)N * DIMC;                // MPAD*1024     (25.2 MB)
    ushort* qb  = (ushort*)d_out;                        // q lives in d_out (bf16)

    // convert + pad x
    cvt_pad<<<2048, 256, 0, stream>>>(x, xb, N * DIMC, MPAD * DIMC);
    // transpose+convert weights
    dim3 tg(32, 32);
    transpose_w_kernel<<<tg, 256, 0, stream>>>(Wq, wtq);
    transpose_w_kernel<<<tg, 256, 0, stream>>>(Wk, wtk);
    transpose_w_kernel<<<tg, 256, 0, stream>>>(Wv, wtv);
    transpose_w_kernel<<<tg, 256, 0, stream>>>(Wu, wtu);

    // QKV projections (bf16 out)
    gemm_mfma<true><<<768, 256, 0, stream>>>(xb, wtq, bq, qb, N);
    gemm_mfma<true><<<768, 256, 0, stream>>>(xb, wtk, bk, kb, N);
    gemm_mfma<true><<<768, 256, 0, stream>>>(xb, wtv, bv, vb, N);

    // attention (bf16 in, bf16 out in place into vb)
    attn_kernel<<<dim3(B * NHEAD), dim3(256), 0, stream>>>(qb, kb, vb, lens);

    // output projection (fp32 out to d_out)
    gemm_mfma<false><<<768, 256, 0, stream>>>(vb, wtu, bu, d_out, N);
}

// Round 4
// 273.560 us; speedup vs baseline: 6.0894x; 1.7439x over previous
//
#include <hip/hip_runtime.h>
#include <hip/hip_bf16.h>
#include <math.h>

#define DIMC 1024
#define NHEAD 16
#define HDIM 64
#define MPAD 12288   // 12224 padded up to multiple of 128

using bf16x8 = __attribute__((ext_vector_type(8))) short;
using f32x4  = __attribute__((ext_vector_type(4))) float;
using f32x16 = __attribute__((ext_vector_type(16))) float;

__device__ inline ushort f2bf(float f) {          // round-to-nearest-even
    uint u = __float_as_uint(f);
    u += 0x7fffu + ((u >> 16) & 1u);
    return (ushort)(u >> 16);
}

__device__ inline uint pkbf(float a, float b) {   // pack 2 f32 -> 2 bf16 (lo=a)
    __hip_bfloat162 t = __float22bfloat162_rn(float2{a, b});
    return *reinterpret_cast<uint*>(&t);
}

__device__ inline void gload_lds16(const ushort* g, ushort* l) {
    __builtin_amdgcn_global_load_lds(
        (const __attribute__((address_space(1))) uint*)g,
        (__attribute__((address_space(3))) uint*)l, 16, 0, 0);
}

// ---------------------------------------------------------------------------
// bf16 MFMA GEMM: C[M x 1024] = A[Mpad x 1024](bf16) * Bt[1024 x 1024]^T(bf16) + bias
// 128x128 tile, BK=32, 4 waves.  (m97 structure; verified passing in round 1/2)
// ---------------------------------------------------------------------------
template <bool BF16OUT>
__global__ __launch_bounds__(256) void gemm_mfma(
    const ushort* __restrict__ A, const ushort* __restrict__ Bt,
    const float* __restrict__ bias, void* __restrict__ Cout, int M)
{
    __shared__ ushort As[128 * 32];
    __shared__ ushort Bs[128 * 32];

    const int bid = blockIdx.x;
    const int cpx = gridDim.x >> 3;                 // 96
    const int swz = (bid & 7) * cpx + (bid >> 3);
    const int mt  = swz % 96;
    const int nt  = swz / 96;
    const int row0 = mt * 128, col0 = nt * 128;

    const int t    = threadIdx.x;
    const int w    = t >> 6;
    const int lane = t & 63;
    const int wr   = (w >> 1) * 64;
    const int wc   = (w & 1) * 64;
    const int frow = lane & 15;
    const int fk   = (lane >> 4) * 8;

    const int arow = lane >> 2;
    const int acol = (lane & 3) * 8;

    f32x4 acc[4][4] = {};

    for (int k0 = 0; k0 < DIMC; k0 += 32) {
        #pragma unroll
        for (int i = 0; i < 2; ++i) {
            const int rr = (i * 4 + w) * 16;
            gload_lds16(A  + (size_t)(row0 + rr + arow) * DIMC + k0 + acol, As + rr * 32);
            gload_lds16(Bt + (size_t)(col0 + rr + arow) * DIMC + k0 + acol, Bs + rr * 32);
        }
        __syncthreads();

        bf16x8 af[4], bfr[4];
        #pragma unroll
        for (int m = 0; m < 4; ++m)
            af[m]  = *(const bf16x8*)&As[(wr + m * 16 + frow) * 32 + fk];
        #pragma unroll
        for (int n = 0; n < 4; ++n)
            bfr[n] = *(const bf16x8*)&Bs[(wc + n * 16 + frow) * 32 + fk];

        #pragma unroll
        for (int m = 0; m < 4; ++m)
            #pragma unroll
            for (int n = 0; n < 4; ++n)
                acc[m][n] = __builtin_amdgcn_mfma_f32_16x16x32_bf16(
                    af[m], bfr[n], acc[m][n], 0, 0, 0);
        __syncthreads();
    }

    const int r4 = (lane >> 4) * 4;
    #pragma unroll
    for (int n = 0; n < 4; ++n) {
        const int c  = col0 + wc + n * 16 + (lane & 15);
        const float bb = bias[c];
        #pragma unroll
        for (int m = 0; m < 4; ++m) {
            #pragma unroll
            for (int r = 0; r < 4; ++r) {
                const int gr = row0 + wr + m * 16 + r4 + r;
                if (gr < M) {
                    const float val = acc[m][n][r] + bb;
                    if (BF16OUT) ((ushort*)Cout)[(size_t)gr * DIMC + c] = f2bf(val);
                    else         ((float*)Cout)[(size_t)gr * DIMC + c]  = val;
                }
            }
        }
    }
}

// ---------------------------------------------------------------------------
__global__ __launch_bounds__(256) void cvt_pad(
    const float* __restrict__ x, ushort* __restrict__ xb, int nvalid, int ntot)
{
    const int stride = gridDim.x * blockDim.x;
    for (int i = blockIdx.x * blockDim.x + threadIdx.x; i < ntot / 4; i += stride) {
        const int e = i * 4;
        ushort4 o;
        if (e < nvalid) {
            const float4 f = *(const float4*)(x + e);
            o.x = f2bf(f.x); o.y = f2bf(f.y); o.z = f2bf(f.z); o.w = f2bf(f.w);
        } else { o.x = o.y = o.z = o.w = 0; }
        *(ushort4*)(xb + e) = o;
    }
}

__global__ __launch_bounds__(256) void transpose_w_kernel(
    const float* __restrict__ W, ushort* __restrict__ Wt)
{
    __shared__ float tile[32][33];
    const int tx = threadIdx.x & 31;
    const int ty = threadIdx.x >> 5;
    const int n0 = blockIdx.x * 32;
    const int k0 = blockIdx.y * 32;
    #pragma unroll
    for (int i = 0; i < 32; i += 8)
        tile[ty + i][tx] = W[(size_t)(k0 + ty + i) * DIMC + n0 + tx];
    __syncthreads();
    #pragma unroll
    for (int i = 0; i < 32; i += 8)
        Wt[(size_t)(n0 + ty + i) * DIMC + k0 + tx] = f2bf(tile[tx][ty + i]);
}

// ---------------------------------------------------------------------------
// MFMA flash attention.  One wave per (image, head, 64-query tile).
// S^T = mfma(K, Q) (32x32x16) -> softmax lane-local + shfl_xor(32).
// PV: O^T = mfma(V^T, P); V^T built EXPLICITLY in LDS (stride-68 rows) by a
// transposing stage (global uint4 loads -> in-register repack -> ds_write_b32).
// No inline asm, no tr_read, no barriers (1 wave / block).
// ---------------------------------------------------------------------------
__global__ __launch_bounds__(64) void attn_mfma(
    const ushort* __restrict__ qg, const ushort* __restrict__ kg,
    const ushort* __restrict__ vg, ushort* __restrict__ og,
    const int* __restrict__ lens)
{
    __shared__ ushort Vt[64 * 68];   // V^T tile: Vt[d][key], row stride 68 ushorts

    const int bid = blockIdx.x;
    const int qt  = bid & 3;
    const int bh  = bid >> 2;
    const int h   = bh & 15;
    const int b   = bh >> 4;

    int off = 0;
    for (int i = 0; i < b; ++i) off += lens[i];
    const int L = lens[b];
    if (qt * 64 >= L) return;
    const int ntk = (L + 63) >> 6;

    const int lane = threadIdx.x & 63;
    const int l31  = lane & 31;
    const int hi   = lane >> 5;
    const int kp   = lane & 31;      // key-pair id for V staging
    const int dh   = lane >> 5;      // d-half for V staging

    const float scale = 0.03125f;    // 1/sqrt(1024)

    // Q fragments (B-operand): lane holds Q[q=qt*64+qn*32+l31][d=ks*16+hi*8 ..+8]
    bf16x8 qf[2][4];
    #pragma unroll
    for (int qn = 0; qn < 2; ++qn) {
        const size_t row = (size_t)(off + min(qt * 64 + qn * 32 + l31, L - 1));
        #pragma unroll
        for (int ks = 0; ks < 4; ++ks)
            qf[qn][ks] = *(const bf16x8*)(qg + row * DIMC + h * HDIM + ks * 16 + hi * 8);
    }

    f32x16 o[2][2] = {};             // O^T acc [dm][qn]: row d=dm*32+(r&3)+8(r>>2)+4hi, col q
    float mst[2] = {-1e30f, -1e30f};
    float lst[2] = {0.f, 0.f};

    for (int t = 0; t < ntk; ++t) {
        const int j0 = t * 64;

        // ---- issue V-tile global loads first (consumed after QK^T) ----
        uint4 va[4], vbr[4];
        #pragma unroll
        for (int it = 0; it < 4; ++it) {
            const int d0 = (it * 2 + dh) * 8;
            const size_t r0 = (size_t)(off + min(j0 + 2 * kp,     L - 1));
            const size_t r1 = (size_t)(off + min(j0 + 2 * kp + 1, L - 1));
            va[it]  = *(const uint4*)(vg + r0 * DIMC + h * HDIM + d0);
            vbr[it] = *(const uint4*)(vg + r1 * DIMC + h * HDIM + d0);
        }

        // ---- K fragments (A-operand): K[key=j0+km*32+l31][d=ks*16+hi*8 ..+8] ----
        bf16x8 kf[2][4];
        #pragma unroll
        for (int km = 0; km < 2; ++km) {
            const size_t row = (size_t)(off + min(j0 + km * 32 + l31, L - 1));
            #pragma unroll
            for (int ks = 0; ks < 4; ++ks)
                kf[km][ks] = *(const bf16x8*)(kg + row * DIMC + h * HDIM + ks * 16 + hi * 8);
        }

        // ---- S^T[key][q] = K . Q^T ----
        f32x16 s[2][2] = {};
        #pragma unroll
        for (int km = 0; km < 2; ++km)
            #pragma unroll
            for (int qn = 0; qn < 2; ++qn)
                #pragma unroll
                for (int ks = 0; ks < 4; ++ks)
                    s[km][qn] = __builtin_amdgcn_mfma_f32_32x32x16_bf16(
                        kf[km][ks], qf[qn][ks], s[km][qn], 0, 0, 0);

        // ---- repack V to V^T in LDS (global loads already drained by QK^T) ----
        #pragma unroll
        for (int it = 0; it < 4; ++it) {
            const int d0 = (it * 2 + dh) * 8;
            const uint a4[4] = {va[it].x,  va[it].y,  va[it].z,  va[it].w};
            const uint b4[4] = {vbr[it].x, vbr[it].y, vbr[it].z, vbr[it].w};
            #pragma unroll
            for (int jj = 0; jj < 4; ++jj) {
                const uint lo = (a4[jj] & 0xffffu) | (b4[jj] << 16);          // d0+2jj
                const uint hi2 = (a4[jj] >> 16) | (b4[jj] & 0xffff0000u);     // d0+2jj+1
                *(uint*)&Vt[(d0 + 2 * jj)     * 68 + 2 * kp] = lo;
                *(uint*)&Vt[(d0 + 2 * jj + 1) * 68 + 2 * kp] = hi2;
            }
        }

        // ---- online softmax (VALU; hides LDS write latency) ----
        #pragma unroll
        for (int qn = 0; qn < 2; ++qn) {
            float tm = -1e30f;
            #pragma unroll
            for (int km = 0; km < 2; ++km)
                #pragma unroll
                for (int r = 0; r < 16; ++r) {
                    const int key = j0 + km * 32 + (r & 3) + 8 * (r >> 2) + 4 * hi;
                    float sv = s[km][qn][r] * scale;
                    sv = (key < L) ? sv : -1e30f;
                    s[km][qn][r] = sv;
                    tm = fmaxf(tm, sv);
                }
            tm = fmaxf(tm, __shfl_xor(tm, 32));
            const float nm = fmaxf(mst[qn], tm);
            const float corr = __expf(mst[qn] - nm);
            mst[qn] = nm;
            float ls = 0.f;
            #pragma unroll
            for (int km = 0; km < 2; ++km)
                #pragma unroll
                for (int r = 0; r < 16; ++r) {
                    const float p = __expf(s[km][qn][r] - nm);
                    s[km][qn][r] = p;
                    ls += p;
                }
            ls += __shfl_xor(ls, 32);
            lst[qn] = lst[qn] * corr + ls;
            #pragma unroll
            for (int dm = 0; dm < 2; ++dm)
                #pragma unroll
                for (int r = 0; r < 16; ++r)
                    o[dm][qn][r] *= corr;
        }

        // ---- PV: O^T += V^T * P  (4 k-steps of 16 keys) ----
        #pragma unroll
        for (int kspv = 0; kspv < 4; ++kspv) {
            const int km = kspv >> 1;
            const int sb = kspv & 1;

            // A-frags: V^T[d = dm*32 + l31][kspv*16 + hi*8 .. +8]  (plain LDS reads)
            bf16x8 Afr[2];
            #pragma unroll
            for (int dm = 0; dm < 2; ++dm) {
                const int d = dm * 32 + l31;
                const uint2 p0 = *(const uint2*)&Vt[d * 68 + kspv * 16 + hi * 8];
                const uint2 p1 = *(const uint2*)&Vt[d * 68 + kspv * 16 + hi * 8 + 4];
                union { uint u[4]; bf16x8 v; } aa;
                aa.u[0] = p0.x; aa.u[1] = p0.y; aa.u[2] = p1.x; aa.u[3] = p1.y;
                Afr[dm] = aa.v;
            }

            // B-operand from P^T register fragments: only l <-> l^32 exchange
            bf16x8 Bfr[2];
            #pragma unroll
            for (int qn = 0; qn < 2; ++qn) {
                const uint X0 = pkbf(s[km][qn][8 * sb + 0], s[km][qn][8 * sb + 1]);
                const uint X1 = pkbf(s[km][qn][8 * sb + 2], s[km][qn][8 * sb + 3]);
                const uint Y0 = pkbf(s[km][qn][8 * sb + 4], s[km][qn][8 * sb + 5]);
                const uint Y1 = pkbf(s[km][qn][8 * sb + 6], s[km][qn][8 * sb + 7]);
                const uint sx0 = (uint)__shfl_xor((int)X0, 32);
                const uint sx1 = (uint)__shfl_xor((int)X1, 32);
                const uint sy0 = (uint)__shfl_xor((int)Y0, 32);
                const uint sy1 = (uint)__shfl_xor((int)Y1, 32);
                union { uint u[4]; bf16x8 v; } bb;
                bb.u[0] = hi ? sy0 : X0;
                bb.u[1] = hi ? sy1 : X1;
                bb.u[2] = hi ? Y0 : sx0;
                bb.u[3] = hi ? Y1 : sx1;
                Bfr[qn] = bb.v;
            }

            #pragma unroll
            for (int dm = 0; dm < 2; ++dm)
                #pragma unroll
                for (int qn = 0; qn < 2; ++qn)
                    o[dm][qn] = __builtin_amdgcn_mfma_f32_32x32x16_bf16(
                        Afr[dm], Bfr[qn], o[dm][qn], 0, 0, 0);
        }
    }

    // ---- epilogue: O^T -> O, divide by l, store bf16 ----
    #pragma unroll
    for (int qn = 0; qn < 2; ++qn) {
        const int q = qt * 64 + qn * 32 + l31;
        if (q < L) {
            const float inv = 1.f / lst[qn];
            ushort* orow = og + (size_t)(off + q) * DIMC + h * HDIM;
            #pragma unroll
            for (int dm = 0; dm < 2; ++dm)
                #pragma unroll
                for (int bq = 0; bq < 4; ++bq) {
                    const int r0 = 4 * bq;
                    uint2 st;
                    st.x = pkbf(o[dm][qn][r0 + 0] * inv, o[dm][qn][r0 + 1] * inv);
                    st.y = pkbf(o[dm][qn][r0 + 2] * inv, o[dm][qn][r0 + 3] * inv);
                    *(uint2*)(orow + dm * 32 + 8 * bq + 4 * hi) = st;
                }
        }
    }
}

// ---------------------------------------------------------------------------
extern "C" void kernel_launch(void* const* d_in, const int* in_sizes, int n_in,
                              void* d_out, int out_size, void* d_ws, size_t ws_size,
                              hipStream_t stream)
{
    const float* x   = (const float*)d_in[0];
    const float* Wq  = (const float*)d_in[1];
    const float* bq  = (const float*)d_in[2];
    const float* Wk  = (const float*)d_in[3];
    const float* bk  = (const float*)d_in[4];
    const float* Wv  = (const float*)d_in[5];
    const float* bv  = (const float*)d_in[6];
    const float* Wu  = (const float*)d_in[7];
    const float* bu  = (const float*)d_in[8];
    const int*  lens = (const int*)d_in[9];

    const int N = in_sizes[0] / DIMC;    // 12224
    const int B = in_sizes[9];           // 64

    ushort* xb  = (ushort*)d_ws;                         // MPAD*1024 bf16
    ushort* wtq = xb  + (size_t)MPAD * DIMC;
    ushort* wtk = wtq + (size_t)DIMC * DIMC;
    ushort* wtv = wtk + (size_t)DIMC * DIMC;
    ushort* wtu = wtv + (size_t)DIMC * DIMC;
    ushort* kb  = wtu + (size_t)DIMC * DIMC;             // N*1024 bf16
    ushort* vb  = kb  + (size_t)N * DIMC;                // N*1024 bf16
    ushort* qb  = (ushort*)d_out;                        // q lives in d_out (bf16)
    ushort* ob  = xb;                                    // attn out reuses xb (x is dead)

    cvt_pad<<<2048, 256, 0, stream>>>(x, xb, N * DIMC, MPAD * DIMC);
    dim3 tg(32, 32);
    transpose_w_kernel<<<tg, 256, 0, stream>>>(Wq, wtq);
    transpose_w_kernel<<<tg, 256, 0, stream>>>(Wk, wtk);
    transpose_w_kernel<<<tg, 256, 0, stream>>>(Wv, wtv);
    transpose_w_kernel<<<tg, 256, 0, stream>>>(Wu, wtu);

    gemm_mfma<true><<<768, 256, 0, stream>>>(xb, wtq, bq, qb, N);
    gemm_mfma<true><<<768, 256, 0, stream>>>(xb, wtk, bk, kb, N);
    gemm_mfma<true><<<768, 256, 0, stream>>>(xb, wtv, bv, vb, N);

    attn_mfma<<<dim3(B * NHEAD * 4), dim3(64), 0, stream>>>(qb, kb, vb, ob, lens);

    gemm_mfma<false><<<768, 256, 0, stream>>>(ob, wtu, bu, d_out, N);
}

// Round 5
// 261.104 us; speedup vs baseline: 6.3799x; 1.0477x over previous
//
#include <hip/hip_runtime.h>
#include <hip/hip_bf16.h>
#include <math.h>

#define DIMC 1024
#define NHEAD 16
#define HDIM 64
#define MPAD 12288   // 12224 padded up to multiple of 128

using bf16x8 = __attribute__((ext_vector_type(8))) short;
using f32x4  = __attribute__((ext_vector_type(4))) float;
using f32x16 = __attribute__((ext_vector_type(16))) float;

__device__ inline ushort f2bf(float f) {          // round-to-nearest-even
    uint u = __float_as_uint(f);
    u += 0x7fffu + ((u >> 16) & 1u);
    return (ushort)(u >> 16);
}
__device__ inline float bf2f(ushort h) { return __uint_as_float(((uint)h) << 16); }

__device__ inline uint pkbf(float a, float b) {   // pack 2 f32 -> 2 bf16 (lo=a)
    __hip_bfloat162 t = __float22bfloat162_rn(float2{a, b});
    return *reinterpret_cast<uint*>(&t);
}

__device__ inline void gload_lds16(const ushort* g, ushort* l) {
    __builtin_amdgcn_global_load_lds(
        (const __attribute__((address_space(1))) uint*)g,
        (__attribute__((address_space(3))) uint*)l, 16, 0, 0);
}

// ---------------------------------------------------------------------------
// Fused QKV GEMM: A[MPAD x 1024] (bf16) x Wt_cat[3072 x 1024]^T + bias ->
// three bf16 outputs (q,k,v).  128x128 tile, BK=32, 4 waves (m97 structure).
// Wt_cat = wtq|wtk|wtv contiguous.  grid = 96*24 = 2304 blocks.
// ---------------------------------------------------------------------------
__global__ __launch_bounds__(256) void gemm_qkv(
    const ushort* __restrict__ A, const ushort* __restrict__ Bt,
    const float* __restrict__ bq, const float* __restrict__ bk,
    const float* __restrict__ bv,
    ushort* __restrict__ qb, ushort* __restrict__ kb, ushort* __restrict__ vb,
    int M)
{
    __shared__ ushort As[128 * 32];
    __shared__ ushort Bs[128 * 32];

    const int bid = blockIdx.x;
    const int cpx = gridDim.x >> 3;                 // 288
    const int swz = (bid & 7) * cpx + (bid >> 3);
    const int mt  = swz % 96;
    const int nt  = swz / 96;                       // 0..23
    const int row0 = mt * 128, col0 = nt * 128;     // col0 in [0,3072)

    const int t    = threadIdx.x;
    const int w    = t >> 6;
    const int lane = t & 63;
    const int wr   = (w >> 1) * 64;
    const int wc   = (w & 1) * 64;
    const int frow = lane & 15;
    const int fk   = (lane >> 4) * 8;
    const int arow = lane >> 2;
    const int acol = (lane & 3) * 8;

    f32x4 acc[4][4] = {};

    for (int k0 = 0; k0 < DIMC; k0 += 32) {
        #pragma unroll
        for (int i = 0; i < 2; ++i) {
            const int rr = (i * 4 + w) * 16;
            gload_lds16(A  + (size_t)(row0 + rr + arow) * DIMC + k0 + acol, As + rr * 32);
            gload_lds16(Bt + (size_t)(col0 + rr + arow) * DIMC + k0 + acol, Bs + rr * 32);
        }
        __syncthreads();

        bf16x8 af[4], bfr[4];
        #pragma unroll
        for (int m = 0; m < 4; ++m)
            af[m]  = *(const bf16x8*)&As[(wr + m * 16 + frow) * 32 + fk];
        #pragma unroll
        for (int n = 0; n < 4; ++n)
            bfr[n] = *(const bf16x8*)&Bs[(wc + n * 16 + frow) * 32 + fk];

        #pragma unroll
        for (int m = 0; m < 4; ++m)
            #pragma unroll
            for (int n = 0; n < 4; ++n)
                acc[m][n] = __builtin_amdgcn_mfma_f32_16x16x32_bf16(
                    af[m], bfr[n], acc[m][n], 0, 0, 0);
        __syncthreads();
    }

    const int sel = nt >> 3;                         // 0:q 1:k 2:v
    const float* bias = (sel == 0) ? bq : (sel == 1) ? bk : bv;
    ushort* outp      = (sel == 0) ? qb : (sel == 1) ? kb : vb;
    const int colb = col0 - sel * 1024;

    const int r4 = (lane >> 4) * 4;
    #pragma unroll
    for (int n = 0; n < 4; ++n) {
        const int c  = colb + wc + n * 16 + (lane & 15);
        const float bb = bias[c];
        #pragma unroll
        for (int m = 0; m < 4; ++m) {
            #pragma unroll
            for (int r = 0; r < 4; ++r) {
                const int gr = row0 + wr + m * 16 + r4 + r;
                if (gr < M)
                    outp[(size_t)gr * DIMC + c] = f2bf(acc[m][n][r] + bb);
            }
        }
    }
}

// ---------------------------------------------------------------------------
// Final GEMM (fp32 out): C = A(bf16) x Bt^T + bias.  128x128 tile.
// ---------------------------------------------------------------------------
__global__ __launch_bounds__(256) void gemm_final(
    const ushort* __restrict__ A, const ushort* __restrict__ Bt,
    const float* __restrict__ bias, float* __restrict__ C, int M)
{
    __shared__ ushort As[128 * 32];
    __shared__ ushort Bs[128 * 32];

    const int bid = blockIdx.x;
    const int cpx = gridDim.x >> 3;                 // 96
    const int swz = (bid & 7) * cpx + (bid >> 3);
    const int mt  = swz % 96;
    const int nt  = swz / 96;
    const int row0 = mt * 128, col0 = nt * 128;

    const int t    = threadIdx.x;
    const int w    = t >> 6;
    const int lane = t & 63;
    const int wr   = (w >> 1) * 64;
    const int wc   = (w & 1) * 64;
    const int frow = lane & 15;
    const int fk   = (lane >> 4) * 8;
    const int arow = lane >> 2;
    const int acol = (lane & 3) * 8;

    f32x4 acc[4][4] = {};

    for (int k0 = 0; k0 < DIMC; k0 += 32) {
        #pragma unroll
        for (int i = 0; i < 2; ++i) {
            const int rr = (i * 4 + w) * 16;
            gload_lds16(A  + (size_t)(row0 + rr + arow) * DIMC + k0 + acol, As + rr * 32);
            gload_lds16(Bt + (size_t)(col0 + rr + arow) * DIMC + k0 + acol, Bs + rr * 32);
        }
        __syncthreads();

        bf16x8 af[4], bfr[4];
        #pragma unroll
        for (int m = 0; m < 4; ++m)
            af[m]  = *(const bf16x8*)&As[(wr + m * 16 + frow) * 32 + fk];
        #pragma unroll
        for (int n = 0; n < 4; ++n)
            bfr[n] = *(const bf16x8*)&Bs[(wc + n * 16 + frow) * 32 + fk];

        #pragma unroll
        for (int m = 0; m < 4; ++m)
            #pragma unroll
            for (int n = 0; n < 4; ++n)
                acc[m][n] = __builtin_amdgcn_mfma_f32_16x16x32_bf16(
                    af[m], bfr[n], acc[m][n], 0, 0, 0);
        __syncthreads();
    }

    const int r4 = (lane >> 4) * 4;
    #pragma unroll
    for (int n = 0; n < 4; ++n) {
        const int c  = col0 + wc + n * 16 + (lane & 15);
        const float bb = bias[c];
        #pragma unroll
        for (int m = 0; m < 4; ++m) {
            #pragma unroll
            for (int r = 0; r < 4; ++r) {
                const int gr = row0 + wr + m * 16 + r4 + r;
                if (gr < M)
                    C[(size_t)gr * DIMC + c] = acc[m][n][r] + bb;
            }
        }
    }
}

// ---------------------------------------------------------------------------
__global__ __launch_bounds__(256) void cvt_pad(
    const float* __restrict__ x, ushort* __restrict__ xb, int nvalid, int ntot)
{
    const int stride = gridDim.x * blockDim.x;
    for (int i = blockIdx.x * blockDim.x + threadIdx.x; i < ntot / 4; i += stride) {
        const int e = i * 4;
        ushort4 o;
        if (e < nvalid) {
            const float4 f = *(const float4*)(x + e);
            o.x = f2bf(f.x); o.y = f2bf(f.y); o.z = f2bf(f.z); o.w = f2bf(f.w);
        } else { o.x = o.y = o.z = o.w = 0; }
        *(ushort4*)(xb + e) = o;
    }
}

// all 4 weight transposes in one launch (blockIdx.z selects the matrix)
__global__ __launch_bounds__(256) void transpose_w4(
    const float* __restrict__ W0, const float* __restrict__ W1,
    const float* __restrict__ W2, const float* __restrict__ W3,
    ushort* __restrict__ T0, ushort* __restrict__ T1,
    ushort* __restrict__ T2, ushort* __restrict__ T3)
{
    __shared__ float tile[32][33];
    const int z = blockIdx.z;
    const float* W = (z == 0) ? W0 : (z == 1) ? W1 : (z == 2) ? W2 : W3;
    ushort*      T = (z == 0) ? T0 : (z == 1) ? T1 : (z == 2) ? T2 : T3;
    const int tx = threadIdx.x & 31;
    const int ty = threadIdx.x >> 5;
    const int n0 = blockIdx.x * 32;
    const int k0 = blockIdx.y * 32;
    #pragma unroll
    for (int i = 0; i < 32; i += 8)
        tile[ty + i][tx] = W[(size_t)(k0 + ty + i) * DIMC + n0 + tx];
    __syncthreads();
    #pragma unroll
    for (int i = 0; i < 32; i += 8)
        T[(size_t)(n0 + ty + i) * DIMC + k0 + tx] = f2bf(tile[tx][ty + i]);
}

// ---------------------------------------------------------------------------
// MFMA flash attention.  One wave per (image, head, 64-query tile).
// XCD-locality remap: xcd = blockIdx&7 owns a contiguous bh chunk, so the 4
// q-tile waves of each (b,h) (and neighboring heads) share one XCD's L2.
// K register double-buffer; scale folded into Q (exact, 2^-5); defer-max
// (THR=4) skips o-rescale on non-growing tiles; setprio around MFMA.
// ---------------------------------------------------------------------------
__global__ __launch_bounds__(64) void attn_mfma(
    const ushort* __restrict__ qg, const ushort* __restrict__ kg,
    const ushort* __restrict__ vg, ushort* __restrict__ og,
    const int* __restrict__ lens, int B)
{
    __shared__ ushort Vt[64 * 68];   // V^T tile: Vt[d][key], row stride 68 ushorts

    // ---- XCD-aware block remap (grid = B*16*4, 8 | grid) ----
    const int i   = blockIdx.x;
    const int xcd = i & 7;
    const int j   = i >> 3;
    const int bh  = xcd * (B * 2) + (j >> 2);   // B*16/8 = B*2 bh's per XCD
    const int qt  = j & 3;
    const int h   = bh & 15;
    const int b   = bh >> 4;

    const int lane = threadIdx.x & 63;

    // ---- segment offset via wave prefix-scan of lens (B <= 64) ----
    const int myl = (lane < B) ? lens[lane] : 0;
    int inc = myl;
    #pragma unroll
    for (int d = 1; d < 64; d <<= 1) {
        const int nb = __shfl_up(inc, d);
        if (lane >= d) inc += nb;
    }
    const int off = __shfl(inc, b) - __shfl(myl, b);
    const int L   = __shfl(myl, b);
    if (qt * 64 >= L) return;
    const int ntk = (L + 63) >> 6;

    const int l31 = lane & 31;
    const int hi  = lane >> 5;
    const int kp  = lane & 31;       // key-pair id for V staging
    const int dh  = lane >> 5;       // d-half for V staging

    // Q fragments (B-operand) with scale 2^-5 folded in (exact in bf16)
    bf16x8 qf[2][4];
    #pragma unroll
    for (int qn = 0; qn < 2; ++qn) {
        const size_t row = (size_t)(off + min(qt * 64 + qn * 32 + l31, L - 1));
        #pragma unroll
        for (int ks = 0; ks < 4; ++ks) {
            union { uint4 u4; ushort us[8]; bf16x8 v; } tmp;
            tmp.u4 = *(const uint4*)(qg + row * DIMC + h * HDIM + ks * 16 + hi * 8);
            #pragma unroll
            for (int e = 0; e < 8; ++e)
                tmp.us[e] = f2bf(bf2f(tmp.us[e]) * 0.03125f);
            qf[qn][ks] = tmp.v;
        }
    }

    f32x16 o[2][2] = {};             // O^T acc [dm][qn]
    float mst[2] = {-1e30f, -1e30f};
    float lst[2] = {0.f, 0.f};

    uint4 va[4], vbr[4];
    auto issueV = [&](int tt) {
        const int j0s = tt * 64;
        #pragma unroll
        for (int it = 0; it < 4; ++it) {
            const int d0 = (it * 2 + dh) * 8;
            const size_t r0 = (size_t)(off + min(j0s + 2 * kp,     L - 1));
            const size_t r1 = (size_t)(off + min(j0s + 2 * kp + 1, L - 1));
            va[it]  = *(const uint4*)(vg + r0 * DIMC + h * HDIM + d0);
            vbr[it] = *(const uint4*)(vg + r1 * DIMC + h * HDIM + d0);
        }
    };

    bf16x8 kfc[2][4], kfn[2][4];
    auto loadK = [&](int tt, bf16x8 (&kf)[2][4]) {
        const int j0s = tt * 64;
        #pragma unroll
        for (int km = 0; km < 2; ++km) {
            const size_t row = (size_t)(off + min(j0s + km * 32 + l31, L - 1));
            #pragma unroll
            for (int ks = 0; ks < 4; ++ks)
                kf[km][ks] = *(const bf16x8*)(kg + row * DIMC + h * HDIM + ks * 16 + hi * 8);
        }
    };

    issueV(0);
    loadK(0, kfc);

    for (int t = 0; t < ntk; ++t) {
        const int j0 = t * 64;

        // prefetch next K tile (register double-buffer)
        loadK(min(t + 1, ntk - 1), kfn);

        // ---- S^T[key][q] = K . Q^T (scale pre-folded) ----
        f32x16 s[2][2] = {};
        __builtin_amdgcn_s_setprio(1);
        #pragma unroll
        for (int km = 0; km < 2; ++km)
            #pragma unroll
            for (int qn = 0; qn < 2; ++qn)
                #pragma unroll
                for (int ks = 0; ks < 4; ++ks)
                    s[km][qn] = __builtin_amdgcn_mfma_f32_32x32x16_bf16(
                        kfc[km][ks], qf[qn][ks], s[km][qn], 0, 0, 0);
        __builtin_amdgcn_s_setprio(0);

        // ---- repack V(t) to V^T in LDS ----
        #pragma unroll
        for (int it = 0; it < 4; ++it) {
            const int d0 = (it * 2 + dh) * 8;
            const uint a4[4] = {va[it].x,  va[it].y,  va[it].z,  va[it].w};
            const uint b4[4] = {vbr[it].x, vbr[it].y, vbr[it].z, vbr[it].w};
            #pragma unroll
            for (int jj = 0; jj < 4; ++jj) {
                const uint lo  = (a4[jj] & 0xffffu) | (b4[jj] << 16);
                const uint hi2 = (a4[jj] >> 16) | (b4[jj] & 0xffff0000u);
                *(uint*)&Vt[(d0 + 2 * jj)     * 68 + 2 * kp] = lo;
                *(uint*)&Vt[(d0 + 2 * jj + 1) * 68 + 2 * kp] = hi2;
            }
        }
        if (t + 1 < ntk) issueV(t + 1);

        // ---- online softmax with defer-max ----
        const bool fullTile = (j0 + 64 <= L);
        float tmv[2];
        #pragma unroll
        for (int qn = 0; qn < 2; ++qn) {
            float tm = -1e30f;
            if (fullTile) {
                #pragma unroll
                for (int km = 0; km < 2; ++km)
                    #pragma unroll
                    for (int r = 0; r < 16; ++r)
                        tm = fmaxf(tm, s[km][qn][r]);
            } else {
                #pragma unroll
                for (int km = 0; km < 2; ++km)
                    #pragma unroll
                    for (int r = 0; r < 16; ++r) {
                        const int key = j0 + km * 32 + (r & 3) + 8 * (r >> 2) + 4 * hi;
                        float sv = s[km][qn][r];
                        sv = (key < L) ? sv : -1e30f;
                        s[km][qn][r] = sv;
                        tm = fmaxf(tm, sv);
                    }
            }
            tm = fmaxf(tm, __shfl_xor(tm, 32));
            tmv[qn] = tm;
        }

        const bool need = (tmv[0] > mst[0] + 4.f) || (tmv[1] > mst[1] + 4.f);
        if (__any(need)) {
            #pragma unroll
            for (int qn = 0; qn < 2; ++qn) {
                const float nm = fmaxf(mst[qn], tmv[qn]);
                const float corr = __expf(mst[qn] - nm);
                mst[qn] = nm;
                lst[qn] *= corr;
                #pragma unroll
                for (int dm = 0; dm < 2; ++dm)
                    #pragma unroll
                    for (int r = 0; r < 16; ++r)
                        o[dm][qn][r] *= corr;
            }
        }
        #pragma unroll
        for (int qn = 0; qn < 2; ++qn) {
            float ls = 0.f;
            #pragma unroll
            for (int km = 0; km < 2; ++km)
                #pragma unroll
                for (int r = 0; r < 16; ++r) {
                    const float p = __expf(s[km][qn][r] - mst[qn]);
                    s[km][qn][r] = p;
                    ls += p;
                }
            ls += __shfl_xor(ls, 32);
            lst[qn] += ls;
        }

        // ---- PV: O^T += V^T * P ----
        #pragma unroll
        for (int kspv = 0; kspv < 4; ++kspv) {
            const int km = kspv >> 1;
            const int sb = kspv & 1;

            bf16x8 Afr[2];
            #pragma unroll
            for (int dm = 0; dm < 2; ++dm) {
                const int d = dm * 32 + l31;
                const uint2 p0 = *(const uint2*)&Vt[d * 68 + kspv * 16 + hi * 8];
                const uint2 p1 = *(const uint2*)&Vt[d * 68 + kspv * 16 + hi * 8 + 4];
                union { uint u[4]; bf16x8 v; } aa;
                aa.u[0] = p0.x; aa.u[1] = p0.y; aa.u[2] = p1.x; aa.u[3] = p1.y;
                Afr[dm] = aa.v;
            }

            bf16x8 Bfr[2];
            #pragma unroll
            for (int qn = 0; qn < 2; ++qn) {
                const uint X0 = pkbf(s[km][qn][8 * sb + 0], s[km][qn][8 * sb + 1]);
                const uint X1 = pkbf(s[km][qn][8 * sb + 2], s[km][qn][8 * sb + 3]);
                const uint Y0 = pkbf(s[km][qn][8 * sb + 4], s[km][qn][8 * sb + 5]);
                const uint Y1 = pkbf(s[km][qn][8 * sb + 6], s[km][qn][8 * sb + 7]);
                const uint sx0 = (uint)__shfl_xor((int)X0, 32);
                const uint sx1 = (uint)__shfl_xor((int)X1, 32);
                const uint sy0 = (uint)__shfl_xor((int)Y0, 32);
                const uint sy1 = (uint)__shfl_xor((int)Y1, 32);
                union { uint u[4]; bf16x8 v; } bb;
                bb.u[0] = hi ? sy0 : X0;
                bb.u[1] = hi ? sy1 : X1;
                bb.u[2] = hi ? Y0 : sx0;
                bb.u[3] = hi ? Y1 : sx1;
                Bfr[qn] = bb.v;
            }

            __builtin_amdgcn_s_setprio(1);
            #pragma unroll
            for (int dm = 0; dm < 2; ++dm)
                #pragma unroll
                for (int qn = 0; qn < 2; ++qn)
                    o[dm][qn] = __builtin_amdgcn_mfma_f32_32x32x16_bf16(
                        Afr[dm], Bfr[qn], o[dm][qn], 0, 0, 0);
            __builtin_amdgcn_s_setprio(0);
        }

        // rotate K buffers
        #pragma unroll
        for (int km = 0; km < 2; ++km)
            #pragma unroll
            for (int ks = 0; ks < 4; ++ks)
                kfc[km][ks] = kfn[km][ks];
    }

    // ---- epilogue ----
    #pragma unroll
    for (int qn = 0; qn < 2; ++qn) {
        const int q = qt * 64 + qn * 32 + l31;
        if (q < L) {
            const float inv = 1.f / lst[qn];
            ushort* orow = og + (size_t)(off + q) * DIMC + h * HDIM;
            #pragma unroll
            for (int dm = 0; dm < 2; ++dm)
                #pragma unroll
                for (int bq2 = 0; bq2 < 4; ++bq2) {
                    const int r0 = 4 * bq2;
                    uint2 st;
                    st.x = pkbf(o[dm][qn][r0 + 0] * inv, o[dm][qn][r0 + 1] * inv);
                    st.y = pkbf(o[dm][qn][r0 + 2] * inv, o[dm][qn][r0 + 3] * inv);
                    *(uint2*)(orow + dm * 32 + 8 * bq2 + 4 * hi) = st;
                }
        }
    }
}

// ---------------------------------------------------------------------------
extern "C" void kernel_launch(void* const* d_in, const int* in_sizes, int n_in,
                              void* d_out, int out_size, void* d_ws, size_t ws_size,
                              hipStream_t stream)
{
    const float* x   = (const float*)d_in[0];
    const float* Wq  = (const float*)d_in[1];
    const float* bq  = (const float*)d_in[2];
    const float* Wk  = (const float*)d_in[3];
    const float* bk  = (const float*)d_in[4];
    const float* Wv  = (const float*)d_in[5];
    const float* bv  = (const float*)d_in[6];
    const float* Wu  = (const float*)d_in[7];
    const float* bu  = (const float*)d_in[8];
    const int*  lens = (const int*)d_in[9];

    const int N = in_sizes[0] / DIMC;    // 12224
    const int B = in_sizes[9];           // 64

    ushort* xb  = (ushort*)d_ws;                         // MPAD*1024 bf16
    ushort* wtq = xb  + (size_t)MPAD * DIMC;             // 3 contiguous = Wt_cat
    ushort* wtk = wtq + (size_t)DIMC * DIMC;
    ushort* wtv = wtk + (size_t)DIMC * DIMC;
    ushort* wtu = wtv + (size_t)DIMC * DIMC;
    ushort* kb  = wtu + (size_t)DIMC * DIMC;             // N*1024 bf16
    ushort* vb  = kb  + (size_t)N * DIMC;                // N*1024 bf16
    ushort* qb  = (ushort*)d_out;                        // q lives in d_out (bf16)
    ushort* ob  = xb;                                    // attn out reuses xb

    cvt_pad<<<2048, 256, 0, stream>>>(x, xb, N * DIMC, MPAD * DIMC);
    transpose_w4<<<dim3(32, 32, 4), 256, 0, stream>>>(Wq, Wk, Wv, Wu,
                                                      wtq, wtk, wtv, wtu);

    gemm_qkv<<<2304, 256, 0, stream>>>(xb, wtq, bq, bk, bv, qb, kb, vb, N);

    attn_mfma<<<dim3(B * NHEAD * 4), dim3(64), 0, stream>>>(qb, kb, vb, ob, lens, B);

    gemm_final<<<768, 256, 0, stream>>>(ob, wtu, bu, (float*)d_out, N);
}

// Round 6
// 241.515 us; speedup vs baseline: 6.8974x; 1.0811x over previous
//
#include <hip/hip_runtime.h>
#include <hip/hip_bf16.h>
#include <math.h>

#define DIMC 1024
#define NHEAD 16
#define HDIM 64
#define MPAD 12288   // 12224 padded up to multiple of 128

using bf16x8 = __attribute__((ext_vector_type(8))) short;
using f32x4  = __attribute__((ext_vector_type(4))) float;
using f32x16 = __attribute__((ext_vector_type(16))) float;

__device__ inline ushort f2bf(float f) {          // round-to-nearest-even
    uint u = __float_as_uint(f);
    u += 0x7fffu + ((u >> 16) & 1u);
    return (ushort)(u >> 16);
}
__device__ inline float bf2f(ushort h) { return __uint_as_float(((uint)h) << 16); }

__device__ inline uint pkbf(float a, float b) {   // pack 2 f32 -> 2 bf16 (lo=a)
    __hip_bfloat162 t = __float22bfloat162_rn(float2{a, b});
    return *reinterpret_cast<uint*>(&t);
}

__device__ inline void gload_lds16(const ushort* g, ushort* l) {
    __builtin_amdgcn_global_load_lds(
        (const __attribute__((address_space(1))) uint*)g,
        (__attribute__((address_space(3))) uint*)l, 16, 0, 0);
}

// ---------------------------------------------------------------------------
// Fused QKV GEMM: A[MPAD x 1024] (bf16) x Wt_cat[3072 x 1024]^T + bias ->
// three bf16 outputs (q,k,v).  128x128 tile, BK=32, 4 waves (m97 structure).
// 2-level XCD supertile: each XCD owns 12 mt (A-chunk 3MB, L2-resident) x all
// 24 nt, mt-fast order -> per-XCD fetch = 3MB A + 6.3MB B ~= 9.3MB.
// ---------------------------------------------------------------------------
__global__ __launch_bounds__(256) void gemm_qkv(
    const ushort* __restrict__ A, const ushort* __restrict__ Bt,
    const float* __restrict__ bq, const float* __restrict__ bk,
    const float* __restrict__ bv,
    ushort* __restrict__ qb, ushort* __restrict__ kb, ushort* __restrict__ vb,
    int M)
{
    __shared__ ushort As[128 * 32];
    __shared__ ushort Bs[128 * 32];

    const int bid = blockIdx.x;
    const int xcd = bid & 7;
    const int j   = bid >> 3;                       // 0..287
    const int mt  = xcd * 12 + (j % 12);            // 12-mt chunk per XCD
    const int nt  = j / 12;                         // 0..23
    const int row0 = mt * 128, col0 = nt * 128;     // col0 in [0,3072)

    const int t    = threadIdx.x;
    const int w    = t >> 6;
    const int lane = t & 63;
    const int wr   = (w >> 1) * 64;
    const int wc   = (w & 1) * 64;
    const int frow = lane & 15;
    const int fk   = (lane >> 4) * 8;
    const int arow = lane >> 2;
    const int acol = (lane & 3) * 8;

    f32x4 acc[4][4] = {};

    for (int k0 = 0; k0 < DIMC; k0 += 32) {
        #pragma unroll
        for (int i = 0; i < 2; ++i) {
            const int rr = (i * 4 + w) * 16;
            gload_lds16(A  + (size_t)(row0 + rr + arow) * DIMC + k0 + acol, As + rr * 32);
            gload_lds16(Bt + (size_t)(col0 + rr + arow) * DIMC + k0 + acol, Bs + rr * 32);
        }
        __syncthreads();

        bf16x8 af[4], bfr[4];
        #pragma unroll
        for (int m = 0; m < 4; ++m)
            af[m]  = *(const bf16x8*)&As[(wr + m * 16 + frow) * 32 + fk];
        #pragma unroll
        for (int n = 0; n < 4; ++n)
            bfr[n] = *(const bf16x8*)&Bs[(wc + n * 16 + frow) * 32 + fk];

        #pragma unroll
        for (int m = 0; m < 4; ++m)
            #pragma unroll
            for (int n = 0; n < 4; ++n)
                acc[m][n] = __builtin_amdgcn_mfma_f32_16x16x32_bf16(
                    af[m], bfr[n], acc[m][n], 0, 0, 0);
        __syncthreads();
    }

    const int sel = nt >> 3;                         // 0:q 1:k 2:v
    const float* bias = (sel == 0) ? bq : (sel == 1) ? bk : bv;
    ushort* outp      = (sel == 0) ? qb : (sel == 1) ? kb : vb;
    const int colb = col0 - sel * 1024;

    const int r4 = (lane >> 4) * 4;
    #pragma unroll
    for (int n = 0; n < 4; ++n) {
        const int c  = colb + wc + n * 16 + (lane & 15);
        const float bb = bias[c];
        #pragma unroll
        for (int m = 0; m < 4; ++m) {
            #pragma unroll
            for (int r = 0; r < 4; ++r) {
                const int gr = row0 + wr + m * 16 + r4 + r;
                if (gr < M)
                    outp[(size_t)gr * DIMC + c] = f2bf(acc[m][n][r] + bb);
            }
        }
    }
}

// ---------------------------------------------------------------------------
// Final GEMM (fp32 out): C = A(bf16) x Bt^T + bias.  128x128 tile.
// Same 2-level XCD supertile (12 mt x 8 nt per XCD).
// ---------------------------------------------------------------------------
__global__ __launch_bounds__(256) void gemm_final(
    const ushort* __restrict__ A, const ushort* __restrict__ Bt,
    const float* __restrict__ bias, float* __restrict__ C, int M)
{
    __shared__ ushort As[128 * 32];
    __shared__ ushort Bs[128 * 32];

    const int bid = blockIdx.x;
    const int xcd = bid & 7;
    const int j   = bid >> 3;                       // 0..95
    const int mt  = xcd * 12 + (j % 12);
    const int nt  = j / 12;                         // 0..7
    const int row0 = mt * 128, col0 = nt * 128;

    const int t    = threadIdx.x;
    const int w    = t >> 6;
    const int lane = t & 63;
    const int wr   = (w >> 1) * 64;
    const int wc   = (w & 1) * 64;
    const int frow = lane & 15;
    const int fk   = (lane >> 4) * 8;
    const int arow = lane >> 2;
    const int acol = (lane & 3) * 8;

    f32x4 acc[4][4] = {};

    for (int k0 = 0; k0 < DIMC; k0 += 32) {
        #pragma unroll
        for (int i = 0; i < 2; ++i) {
            const int rr = (i * 4 + w) * 16;
            gload_lds16(A  + (size_t)(row0 + rr + arow) * DIMC + k0 + acol, As + rr * 32);
            gload_lds16(Bt + (size_t)(col0 + rr + arow) * DIMC + k0 + acol, Bs + rr * 32);
        }
        __syncthreads();

        bf16x8 af[4], bfr[4];
        #pragma unroll
        for (int m = 0; m < 4; ++m)
            af[m]  = *(const bf16x8*)&As[(wr + m * 16 + frow) * 32 + fk];
        #pragma unroll
        for (int n = 0; n < 4; ++n)
            bfr[n] = *(const bf16x8*)&Bs[(wc + n * 16 + frow) * 32 + fk];

        #pragma unroll
        for (int m = 0; m < 4; ++m)
            #pragma unroll
            for (int n = 0; n < 4; ++n)
                acc[m][n] = __builtin_amdgcn_mfma_f32_16x16x32_bf16(
                    af[m], bfr[n], acc[m][n], 0, 0, 0);
        __syncthreads();
    }

    const int r4 = (lane >> 4) * 4;
    #pragma unroll
    for (int n = 0; n < 4; ++n) {
        const int c  = col0 + wc + n * 16 + (lane & 15);
        const float bb = bias[c];
        #pragma unroll
        for (int m = 0; m < 4; ++m) {
            #pragma unroll
            for (int r = 0; r < 4; ++r) {
                const int gr = row0 + wr + m * 16 + r4 + r;
                if (gr < M)
                    C[(size_t)gr * DIMC + c] = acc[m][n][r] + bb;
            }
        }
    }
}

// ---------------------------------------------------------------------------
__global__ __launch_bounds__(256) void cvt_pad(
    const float* __restrict__ x, ushort* __restrict__ xb, int nvalid, int ntot)
{
    const int stride = gridDim.x * blockDim.x;
    for (int i = blockIdx.x * blockDim.x + threadIdx.x; i < ntot / 4; i += stride) {
        const int e = i * 4;
        ushort4 o;
        if (e < nvalid) {
            const float4 f = *(const float4*)(x + e);
            o.x = f2bf(f.x); o.y = f2bf(f.y); o.z = f2bf(f.z); o.w = f2bf(f.w);
        } else { o.x = o.y = o.z = o.w = 0; }
        *(ushort4*)(xb + e) = o;
    }
}

// all 4 weight transposes in one launch (blockIdx.z selects the matrix)
__global__ __launch_bounds__(256) void transpose_w4(
    const float* __restrict__ W0, const float* __restrict__ W1,
    const float* __restrict__ W2, const float* __restrict__ W3,
    ushort* __restrict__ T0, ushort* __restrict__ T1,
    ushort* __restrict__ T2, ushort* __restrict__ T3)
{
    __shared__ float tile[32][33];
    const int z = blockIdx.z;
    const float* W = (z == 0) ? W0 : (z == 1) ? W1 : (z == 2) ? W2 : W3;
    ushort*      T = (z == 0) ? T0 : (z == 1) ? T1 : (z == 2) ? T2 : T3;
    const int tx = threadIdx.x & 31;
    const int ty = threadIdx.x >> 5;
    const int n0 = blockIdx.x * 32;
    const int k0 = blockIdx.y * 32;
    #pragma unroll
    for (int i = 0; i < 32; i += 8)
        tile[ty + i][tx] = W[(size_t)(k0 + ty + i) * DIMC + n0 + tx];
    __syncthreads();
    #pragma unroll
    for (int i = 0; i < 32; i += 8)
        T[(size_t)(n0 + ty + i) * DIMC + k0 + tx] = f2bf(tile[tx][ty + i]);
}

// ---------------------------------------------------------------------------
// MFMA flash attention.  One wave per (image, head, 64-query tile).
// XCD-locality remap: xcd = blockIdx&7 owns a contiguous bh chunk, so the 4
// q-tile waves of each (b,h) (and neighboring heads) share one XCD's L2.
// K register double-buffer; scale folded into Q (exact, 2^-5); defer-max
// (THR=4) skips o-rescale on non-growing tiles; setprio around MFMA.
// ---------------------------------------------------------------------------
__global__ __launch_bounds__(64) void attn_mfma(
    const ushort* __restrict__ qg, const ushort* __restrict__ kg,
    const ushort* __restrict__ vg, ushort* __restrict__ og,
    const int* __restrict__ lens, int B)
{
    __shared__ ushort Vt[64 * 68];   // V^T tile: Vt[d][key], row stride 68 ushorts

    // ---- XCD-aware block remap (grid = B*16*4, 8 | grid) ----
    const int i   = blockIdx.x;
    const int xcd = i & 7;
    const int j   = i >> 3;
    const int bh  = xcd * (B * 2) + (j >> 2);   // B*16/8 = B*2 bh's per XCD
    const int qt  = j & 3;
    const int h   = bh & 15;
    const int b   = bh >> 4;

    const int lane = threadIdx.x & 63;

    // ---- segment offset via wave prefix-scan of lens (B <= 64) ----
    const int myl = (lane < B) ? lens[lane] : 0;
    int inc = myl;
    #pragma unroll
    for (int d = 1; d < 64; d <<= 1) {
        const int nb = __shfl_up(inc, d);
        if (lane >= d) inc += nb;
    }
    const int off = __shfl(inc, b) - __shfl(myl, b);
    const int L   = __shfl(myl, b);
    if (qt * 64 >= L) return;
    const int ntk = (L + 63) >> 6;

    const int l31 = lane & 31;
    const int hi  = lane >> 5;
    const int kp  = lane & 31;       // key-pair id for V staging
    const int dh  = lane >> 5;       // d-half for V staging

    // Q fragments (B-operand) with scale 2^-5 folded in (exact in bf16)
    bf16x8 qf[2][4];
    #pragma unroll
    for (int qn = 0; qn < 2; ++qn) {
        const size_t row = (size_t)(off + min(qt * 64 + qn * 32 + l31, L - 1));
        #pragma unroll
        for (int ks = 0; ks < 4; ++ks) {
            union { uint4 u4; ushort us[8]; bf16x8 v; } tmp;
            tmp.u4 = *(const uint4*)(qg + row * DIMC + h * HDIM + ks * 16 + hi * 8);
            #pragma unroll
            for (int e = 0; e < 8; ++e)
                tmp.us[e] = f2bf(bf2f(tmp.us[e]) * 0.03125f);
            qf[qn][ks] = tmp.v;
        }
    }

    f32x16 o[2][2] = {};             // O^T acc [dm][qn]
    float mst[2] = {-1e30f, -1e30f};
    float lst[2] = {0.f, 0.f};

    uint4 va[4], vbr[4];
    auto issueV = [&](int tt) {
        const int j0s = tt * 64;
        #pragma unroll
        for (int it = 0; it < 4; ++it) {
            const int d0 = (it * 2 + dh) * 8;
            const size_t r0 = (size_t)(off + min(j0s + 2 * kp,     L - 1));
            const size_t r1 = (size_t)(off + min(j0s + 2 * kp + 1, L - 1));
            va[it]  = *(const uint4*)(vg + r0 * DIMC + h * HDIM + d0);
            vbr[it] = *(const uint4*)(vg + r1 * DIMC + h * HDIM + d0);
        }
    };

    bf16x8 kfc[2][4], kfn[2][4];
    auto loadK = [&](int tt, bf16x8 (&kf)[2][4]) {
        const int j0s = tt * 64;
        #pragma unroll
        for (int km = 0; km < 2; ++km) {
            const size_t row = (size_t)(off + min(j0s + km * 32 + l31, L - 1));
            #pragma unroll
            for (int ks = 0; ks < 4; ++ks)
                kf[km][ks] = *(const bf16x8*)(kg + row * DIMC + h * HDIM + ks * 16 + hi * 8);
        }
    };

    issueV(0);
    loadK(0, kfc);

    for (int t = 0; t < ntk; ++t) {
        const int j0 = t * 64;

        // prefetch next K tile (register double-buffer)
        loadK(min(t + 1, ntk - 1), kfn);

        // ---- S^T[key][q] = K . Q^T (scale pre-folded) ----
        f32x16 s[2][2] = {};
        __builtin_amdgcn_s_setprio(1);
        #pragma unroll
        for (int km = 0; km < 2; ++km)
            #pragma unroll
            for (int qn = 0; qn < 2; ++qn)
                #pragma unroll
                for (int ks = 0; ks < 4; ++ks)
                    s[km][qn] = __builtin_amdgcn_mfma_f32_32x32x16_bf16(
                        kfc[km][ks], qf[qn][ks], s[km][qn], 0, 0, 0);
        __builtin_amdgcn_s_setprio(0);

        // ---- repack V(t) to V^T in LDS ----
        #pragma unroll
        for (int it = 0; it < 4; ++it) {
            const int d0 = (it * 2 + dh) * 8;
            const uint a4[4] = {va[it].x,  va[it].y,  va[it].z,  va[it].w};
            const uint b4[4] = {vbr[it].x, vbr[it].y, vbr[it].z, vbr[it].w};
            #pragma unroll
            for (int jj = 0; jj < 4; ++jj) {
                const uint lo  = (a4[jj] & 0xffffu) | (b4[jj] << 16);
                const uint hi2 = (a4[jj] >> 16) | (b4[jj] & 0xffff0000u);
                *(uint*)&Vt[(d0 + 2 * jj)     * 68 + 2 * kp] = lo;
                *(uint*)&Vt[(d0 + 2 * jj + 1) * 68 + 2 * kp] = hi2;
            }
        }
        if (t + 1 < ntk) issueV(t + 1);

        // ---- online softmax with defer-max ----
        const bool fullTile = (j0 + 64 <= L);
        float tmv[2];
        #pragma unroll
        for (int qn = 0; qn < 2; ++qn) {
            float tm = -1e30f;
            if (fullTile) {
                #pragma unroll
                for (int km = 0; km < 2; ++km)
                    #pragma unroll
                    for (int r = 0; r < 16; ++r)
                        tm = fmaxf(tm, s[km][qn][r]);
            } else {
                #pragma unroll
                for (int km = 0; km < 2; ++km)
                    #pragma unroll
                    for (int r = 0; r < 16; ++r) {
                        const int key = j0 + km * 32 + (r & 3) + 8 * (r >> 2) + 4 * hi;
                        float sv = s[km][qn][r];
                        sv = (key < L) ? sv : -1e30f;
                        s[km][qn][r] = sv;
                        tm = fmaxf(tm, sv);
                    }
            }
            tm = fmaxf(tm, __shfl_xor(tm, 32));
            tmv[qn] = tm;
        }

        const bool need = (tmv[0] > mst[0] + 4.f) || (tmv[1] > mst[1] + 4.f);
        if (__any(need)) {
            #pragma unroll
            for (int qn = 0; qn < 2; ++qn) {
                const float nm = fmaxf(mst[qn], tmv[qn]);
                const float corr = __expf(mst[qn] - nm);
                mst[qn] = nm;
                lst[qn] *= corr;
                #pragma unroll
                for (int dm = 0; dm < 2; ++dm)
                    #pragma unroll
                    for (int r = 0; r < 16; ++r)
                        o[dm][qn][r] *= corr;
            }
        }
        #pragma unroll
        for (int qn = 0; qn < 2; ++qn) {
            float ls = 0.f;
            #pragma unroll
            for (int km = 0; km < 2; ++km)
                #pragma unroll
                for (int r = 0; r < 16; ++r) {
                    const float p = __expf(s[km][qn][r] - mst[qn]);
                    s[km][qn][r] = p;
                    ls += p;
                }
            ls += __shfl_xor(ls, 32);
            lst[qn] += ls;
        }

        // ---- PV: O^T += V^T * P ----
        #pragma unroll
        for (int kspv = 0; kspv < 4; ++kspv) {
            const int km = kspv >> 1;
            const int sb = kspv & 1;

            bf16x8 Afr[2];
            #pragma unroll
            for (int dm = 0; dm < 2; ++dm) {
                const int d = dm * 32 + l31;
                const uint2 p0 = *(const uint2*)&Vt[d * 68 + kspv * 16 + hi * 8];
                const uint2 p1 = *(const uint2*)&Vt[d * 68 + kspv * 16 + hi * 8 + 4];
                union { uint u[4]; bf16x8 v; } aa;
                aa.u[0] = p0.x; aa.u[1] = p0.y; aa.u[2] = p1.x; aa.u[3] = p1.y;
                Afr[dm] = aa.v;
            }

            bf16x8 Bfr[2];
            #pragma unroll
            for (int qn = 0; qn < 2; ++qn) {
                const uint X0 = pkbf(s[km][qn][8 * sb + 0], s[km][qn][8 * sb + 1]);
                const uint X1 = pkbf(s[km][qn][8 * sb + 2], s[km][qn][8 * sb + 3]);
                const uint Y0 = pkbf(s[km][qn][8 * sb + 4], s[km][qn][8 * sb + 5]);
                const uint Y1 = pkbf(s[km][qn][8 * sb + 6], s[km][qn][8 * sb + 7]);
                const uint sx0 = (uint)__shfl_xor((int)X0, 32);
                const uint sx1 = (uint)__shfl_xor((int)X1, 32);
                const uint sy0 = (uint)__shfl_xor((int)Y0, 32);
                const uint sy1 = (uint)__shfl_xor((int)Y1, 32);
                union { uint u[4]; bf16x8 v; } bb;
                bb.u[0] = hi ? sy0 : X0;
                bb.u[1] = hi ? sy1 : X1;
                bb.u[2] = hi ? Y0 : sx0;
                bb.u[3] = hi ? Y1 : sx1;
                Bfr[qn] = bb.v;
            }

            __builtin_amdgcn_s_setprio(1);
            #pragma unroll
            for (int dm = 0; dm < 2; ++dm)
                #pragma unroll
                for (int qn = 0; qn < 2; ++qn)
                    o[dm][qn] = __builtin_amdgcn_mfma_f32_32x32x16_bf16(
                        Afr[dm], Bfr[qn], o[dm][qn], 0, 0, 0);
            __builtin_amdgcn_s_setprio(0);
        }

        // rotate K buffers
        #pragma unroll
        for (int km = 0; km < 2; ++km)
            #pragma unroll
            for (int ks = 0; ks < 4; ++ks)
                kfc[km][ks] = kfn[km][ks];
    }

    // ---- epilogue ----
    #pragma unroll
    for (int qn = 0; qn < 2; ++qn) {
        const int q = qt * 64 + qn * 32 + l31;
        if (q < L) {
            const float inv = 1.f / lst[qn];
            ushort* orow = og + (size_t)(off + q) * DIMC + h * HDIM;
            #pragma unroll
            for (int dm = 0; dm < 2; ++dm)
                #pragma unroll
                for (int bq2 = 0; bq2 < 4; ++bq2) {
                    const int r0 = 4 * bq2;
                    uint2 st;
                    st.x = pkbf(o[dm][qn][r0 + 0] * inv, o[dm][qn][r0 + 1] * inv);
                    st.y = pkbf(o[dm][qn][r0 + 2] * inv, o[dm][qn][r0 + 3] * inv);
                    *(uint2*)(orow + dm * 32 + 8 * bq2 + 4 * hi) = st;
                }
        }
    }
}

// ---------------------------------------------------------------------------
extern "C" void kernel_launch(void* const* d_in, const int* in_sizes, int n_in,
                              void* d_out, int out_size, void* d_ws, size_t ws_size,
                              hipStream_t stream)
{
    const float* x   = (const float*)d_in[0];
    const float* Wq  = (const float*)d_in[1];
    const float* bq  = (const float*)d_in[2];
    const float* Wk  = (const float*)d_in[3];
    const float* bk  = (const float*)d_in[4];
    const float* Wv  = (const float*)d_in[5];
    const float* bv  = (const float*)d_in[6];
    const float* Wu  = (const float*)d_in[7];
    const float* bu  = (const float*)d_in[8];
    const int*  lens = (const int*)d_in[9];

    const int N = in_sizes[0] / DIMC;    // 12224
    const int B = in_sizes[9];           // 64

    ushort* xb  = (ushort*)d_ws;                         // MPAD*1024 bf16
    ushort* wtq = xb  + (size_t)MPAD * DIMC;             // 3 contiguous = Wt_cat
    ushort* wtk = wtq + (size_t)DIMC * DIMC;
    ushort* wtv = wtk + (size_t)DIMC * DIMC;
    ushort* wtu = wtv + (size_t)DIMC * DIMC;
    ushort* kb  = wtu + (size_t)DIMC * DIMC;             // N*1024 bf16
    ushort* vb  = kb  + (size_t)N * DIMC;                // N*1024 bf16
    ushort* qb  = (ushort*)d_out;                        // q lives in d_out (bf16)
    ushort* ob  = xb;                                    // attn out reuses xb

    cvt_pad<<<2048, 256, 0, stream>>>(x, xb, N * DIMC, MPAD * DIMC);
    transpose_w4<<<dim3(32, 32, 4), 256, 0, stream>>>(Wq, Wk, Wv, Wu,
                                                      wtq, wtk, wtv, wtu);

    gemm_qkv<<<2304, 256, 0, stream>>>(xb, wtq, bq, bk, bv, qb, kb, vb, N);

    attn_mfma<<<dim3(B * NHEAD * 4), dim3(64), 0, stream>>>(qb, kb, vb, ob, lens, B);

    gemm_final<<<768, 256, 0, stream>>>(ob, wtu, bu, (float*)d_out, N);
}